// Round 1
// baseline (1221.443 us; speedup 1.0000x reference)
//
#include <hip/hip_runtime.h>

#define N_HALF 8192
#define DIM    256
#define NTOT   16384
#define TILE   128
#define KC     32
#define LDK    36   // padded LDS k-stride (16B aligned rows, breaks bank aliasing)

constexpr float GAMMA = 0.00390625f;  // 1/256

// ---------------- row norms: one wave per row ----------------
__global__ void row_norms_kernel(const float* __restrict__ zs,
                                 const float* __restrict__ zt,
                                 float* __restrict__ n2) {
    int wave = threadIdx.x >> 6;
    int lane = threadIdx.x & 63;
    int row  = blockIdx.x * 4 + wave;
    const float* zp = (row < N_HALF) ? zs + (size_t)row * DIM
                                     : zt + (size_t)(row - N_HALF) * DIM;
    float4 v = *(const float4*)(zp + lane * 4);
    float s = v.x * v.x + v.y * v.y + v.z * v.z + v.w * v.w;
#pragma unroll
    for (int off = 32; off; off >>= 1) s += __shfl_xor(s, off);
    if (lane == 0) n2[row] = s;
}

// ---------------- main: upper-triangle 128x128 tiles ----------------
__global__ void mmd_tile_kernel(const float* __restrict__ zs,
                                const float* __restrict__ zt,
                                const float* __restrict__ n2,
                                double* __restrict__ partial) {
    const int bc  = blockIdx.x;   // column block
    const int br  = blockIdx.y;   // row block
    const int bid = br * gridDim.x + bc;
    const int tid = threadIdx.x;

    if (br > bc) {  // lower triangle: skip (but zero our partial slot)
        if (tid == 0) partial[bid] = 0.0;
        return;
    }

    __shared__ float Xs[TILE][LDK];
    __shared__ float Ys[TILE][LDK];
    __shared__ float wsum[4];

    const int tx = tid & 15;       // 0..15
    const int ty = tid >> 4;       // 0..15
    const int xbase = br * TILE;
    const int ybase = bc * TILE;

    // tiles never straddle the s/t boundary (8192 % 128 == 0)
    const float* xp = (xbase < N_HALF) ? zs + (size_t)xbase * DIM
                                       : zt + (size_t)(xbase - N_HALF) * DIM;
    const float* yp = (ybase < N_HALF) ? zs + (size_t)ybase * DIM
                                       : zt + (size_t)(ybase - N_HALF) * DIM;

    float acc[8][8];
#pragma unroll
    for (int m = 0; m < 8; ++m)
#pragma unroll
        for (int n = 0; n < 8; ++n) acc[m][n] = 0.0f;

    for (int kc = 0; kc < DIM; kc += KC) {
        // stage 128x32 of X and Y into LDS (float4, coalesced)
#pragma unroll
        for (int p = 0; p < 4; ++p) {
            int q  = tid + p * 256;       // 0..1023
            int r  = q >> 3;              // row 0..127
            int c4 = (q & 7) * 4;         // col 0,4,...,28
            float4 xv = *(const float4*)(xp + (size_t)r * DIM + kc + c4);
            float4 yv = *(const float4*)(yp + (size_t)r * DIM + kc + c4);
            *(float4*)&Xs[r][c4] = xv;
            *(float4*)&Ys[r][c4] = yv;
        }
        __syncthreads();

        for (int k = 0; k < KC; k += 4) {
            float4 xv[8], yv[8];
#pragma unroll
            for (int m = 0; m < 8; ++m) xv[m] = *(const float4*)&Xs[ty + 16 * m][k];
#pragma unroll
            for (int n = 0; n < 8; ++n) yv[n] = *(const float4*)&Ys[tx + 16 * n][k];
#pragma unroll
            for (int m = 0; m < 8; ++m)
#pragma unroll
                for (int n = 0; n < 8; ++n) {
                    acc[m][n] = fmaf(xv[m].x, yv[n].x, acc[m][n]);
                    acc[m][n] = fmaf(xv[m].y, yv[n].y, acc[m][n]);
                    acc[m][n] = fmaf(xv[m].z, yv[n].z, acc[m][n]);
                    acc[m][n] = fmaf(xv[m].w, yv[n].w, acc[m][n]);
                }
        }
        __syncthreads();
    }

    // epilogue: d2 = |x|^2 + |y|^2 - 2 x.y, clamp, exp, local sum
    float yn[8];
#pragma unroll
    for (int n = 0; n < 8; ++n) yn[n] = n2[ybase + tx + 16 * n];

    float lsum = 0.0f;
#pragma unroll
    for (int m = 0; m < 8; ++m) {
        float xn = n2[xbase + ty + 16 * m];
#pragma unroll
        for (int n = 0; n < 8; ++n) {
            float d2 = xn + yn[n] - 2.0f * acc[m][n];
            d2 = fmaxf(d2, 0.0f);
            lsum += __expf(-GAMMA * d2);
        }
    }

    // wave reduce (64 lanes), then cross-wave via LDS
#pragma unroll
    for (int off = 32; off; off >>= 1) lsum += __shfl_xor(lsum, off);
    if ((tid & 63) == 0) wsum[tid >> 6] = lsum;
    __syncthreads();
    if (tid == 0) {
        float tot = wsum[0] + wsum[1] + wsum[2] + wsum[3];
        float w = ((xbase < N_HALF) == (ybase < N_HALF)) ? 1.0f : -1.0f;
        if (br != bc) w *= 2.0f;   // symmetric off-diagonal blocks counted twice
        partial[bid] = (double)w * (double)tot;
    }
}

// ---------------- final reduce: 16384 doubles -> scalar ----------------
__global__ void reduce_partials_kernel(const double* __restrict__ partial,
                                       float* __restrict__ out) {
    __shared__ double ws[4];
    double s = 0.0;
    for (int i = threadIdx.x; i < NTOT; i += 256) s += partial[i];
#pragma unroll
    for (int off = 32; off; off >>= 1) s += __shfl_xor(s, off);
    if ((threadIdx.x & 63) == 0) ws[threadIdx.x >> 6] = s;
    __syncthreads();
    if (threadIdx.x == 0) {
        double tot = ws[0] + ws[1] + ws[2] + ws[3];
        out[0] = (float)(tot / ((double)N_HALF * (double)N_HALF));
    }
}

extern "C" void kernel_launch(void* const* d_in, const int* in_sizes, int n_in,
                              void* d_out, int out_size, void* d_ws, size_t ws_size,
                              hipStream_t stream) {
    const float* zs = (const float*)d_in[0];
    const float* zt = (const float*)d_in[1];
    float* out = (float*)d_out;

    float*  n2      = (float*)d_ws;                       // 16384 floats = 64 KB
    double* partial = (double*)((char*)d_ws + 65536);     // 16384 doubles = 128 KB

    row_norms_kernel<<<NTOT / 4, 256, 0, stream>>>(zs, zt, n2);

    dim3 grid(NTOT / TILE, NTOT / TILE);  // 128 x 128 blocks, lower tri early-exits
    mmd_tile_kernel<<<grid, 256, 0, stream>>>(zs, zt, n2, partial);

    reduce_partials_kernel<<<1, 256, 0, stream>>>(partial, out);
}

// Round 2
// 271.339 us; speedup vs baseline: 4.5015x; 4.5015x over previous
//
#include <hip/hip_runtime.h>

#define NH   8192
#define DIM  256
#define NTOT 16384
#define TILE 128
#define NB   (NTOT / TILE)       // 128
#define NTRI (NB * (NB + 1) / 2) // 8256

#define TRIOFF(x) ((x) * (257 - (x)) / 2)

constexpr float GAMMA = 0.00390625f; // 1/256

using short8 = __attribute__((ext_vector_type(8))) short;
using f32x4  = __attribute__((ext_vector_type(4))) float;

__device__ __forceinline__ unsigned short bf16_rne(float f) {
    unsigned u = __float_as_uint(f);
    u += 0x7FFFu + ((u >> 16) & 1u);
    return (unsigned short)(u >> 16);
}

// ---------------- split fp32 -> bf16 hi + bf16 lo ----------------
__global__ void split_kernel(const float* __restrict__ zs,
                             const float* __restrict__ zt,
                             unsigned short* __restrict__ Zh,
                             unsigned short* __restrict__ Zl) {
    size_t i = ((size_t)blockIdx.x * 256 + threadIdx.x) * 8;
    const size_t half = (size_t)NH * DIM;
    const float* src = (i < half) ? (zs + i) : (zt + (i - half));
    float4 v0 = *(const float4*)(src);
    float4 v1 = *(const float4*)(src + 4);
    float x[8] = {v0.x, v0.y, v0.z, v0.w, v1.x, v1.y, v1.z, v1.w};
    short8 hv, lv;
#pragma unroll
    for (int j = 0; j < 8; ++j) {
        unsigned short h = bf16_rne(x[j]);
        float hf = __uint_as_float((unsigned)h << 16);
        hv[j] = (short)h;
        lv[j] = (short)bf16_rne(x[j] - hf);
    }
    *(short8*)(Zh + i) = hv;
    *(short8*)(Zl + i) = lv;
}

// ---------------- row norms (fp32, exact) ----------------
__global__ void row_norms_kernel(const float* __restrict__ zs,
                                 const float* __restrict__ zt,
                                 float* __restrict__ n2) {
    int wave = threadIdx.x >> 6;
    int lane = threadIdx.x & 63;
    int row  = blockIdx.x * 4 + wave;
    const float* zp = (row < NH) ? zs + (size_t)row * DIM
                                 : zt + (size_t)(row - NH) * DIM;
    float4 v = *(const float4*)(zp + lane * 4);
    float s = v.x * v.x + v.y * v.y + v.z * v.z + v.w * v.w;
#pragma unroll
    for (int off = 32; off; off >>= 1) s += __shfl_xor(s, off);
    if (lane == 0) n2[row] = s;
}

// ---------------- main: MFMA bf16x3 over upper-triangle tiles ----------------
__global__ void mmd_mfma_kernel(const unsigned short* __restrict__ Zh,
                                const unsigned short* __restrict__ Zl,
                                const float* __restrict__ n2,
                                double* __restrict__ partial) {
    __shared__ __align__(16) unsigned short lds[4 * 4096]; // Ah, Al, Bh, Bl: 8KB each
    __shared__ double wsum[4];

    const int tid = threadIdx.x;
    const int w = tid >> 6, l = tid & 63;

    // linear block id -> upper-triangle (r, c), r <= c
    int t = blockIdx.x;
    int r = (int)((257.0 - sqrt(257.0 * 257.0 - 8.0 * (double)t)) * 0.5);
    if (r < 0) r = 0;
    if (r > 127) r = 127;
    while (r < 127 && TRIOFF(r + 1) <= t) ++r;
    while (r > 0 && TRIOFF(r) > t) --r;
    const int c = r + (t - TRIOFF(r));
    const int xbase = r * TILE, ybase = c * TILE;

    const unsigned short* gsrc0 = Zh + (size_t)xbase * DIM; // A hi
    const unsigned short* gsrc1 = Zl + (size_t)xbase * DIM; // A lo
    const unsigned short* gsrc2 = Zh + (size_t)ybase * DIM; // B hi
    const unsigned short* gsrc3 = Zl + (size_t)ybase * DIM; // B lo

    const int wr = w >> 1, wc = w & 1;
    const int fr = l & 15;       // fragment row/col within 16
    const int g  = l >> 4;       // k-group 0..3
    const int slotp = g ^ ((fr >> 1) & 3);         // swizzled 16B slot for reads
    const int aoff = (wr * 64 + fr) * 32 + slotp * 8; // shorts; + m*512
    const int boff = (wc * 64 + fr) * 32 + slotp * 8; // shorts; + n*512

    // staging: lane l covers row (l>>2) in a 16-row segment, 16B chunk (l&3),
    // source slot pre-swizzled so linear LDS write == swizzled layout
    const int srow = l >> 2;
    const int scol = ((l & 3) ^ ((l >> 3) & 3)) * 8; // element offset within row

    f32x4 acc[4][4];
#pragma unroll
    for (int m = 0; m < 4; ++m)
#pragma unroll
        for (int n = 0; n < 4; ++n) acc[m][n] = {0.f, 0.f, 0.f, 0.f};

    for (int kc = 0; kc < DIM; kc += 32) {
#pragma unroll
        for (int q = 0; q < 8; ++q) {
            const int b = q >> 1;                 // buffer 0..3
            const int segin = (q & 1) * 4 + w;    // 0..7 (16-row segment)
            const int row = segin * 16 + srow;
            const unsigned short* src =
                (b == 0 ? gsrc0 : b == 1 ? gsrc1 : b == 2 ? gsrc2 : gsrc3)
                + (size_t)row * DIM + kc + scol;
            __builtin_amdgcn_global_load_lds(src, &lds[b * 4096 + segin * 512], 16, 0, 0);
        }
        __syncthreads();

        short8 ah[4], al[4];
#pragma unroll
        for (int m = 0; m < 4; ++m) {
            ah[m] = *(const short8*)&lds[0 * 4096 + aoff + m * 512];
            al[m] = *(const short8*)&lds[1 * 4096 + aoff + m * 512];
        }
#pragma unroll
        for (int n = 0; n < 4; ++n) {
            short8 bh = *(const short8*)&lds[2 * 4096 + boff + n * 512];
            short8 bl = *(const short8*)&lds[3 * 4096 + boff + n * 512];
#pragma unroll
            for (int m = 0; m < 4; ++m) {
                acc[m][n] = __builtin_amdgcn_mfma_f32_16x16x32_bf16(ah[m], bh, acc[m][n], 0, 0, 0);
                acc[m][n] = __builtin_amdgcn_mfma_f32_16x16x32_bf16(ah[m], bl, acc[m][n], 0, 0, 0);
                acc[m][n] = __builtin_amdgcn_mfma_f32_16x16x32_bf16(al[m], bh, acc[m][n], 0, 0, 0);
            }
        }
        __syncthreads();
    }

    // epilogue: d2 = |x|^2+|y|^2-2 x.y, exp, sum
    // C/D layout (m89): col = lane&15, row = (lane>>4)*4 + reg
    float yn[4];
#pragma unroll
    for (int n = 0; n < 4; ++n) yn[n] = n2[ybase + wc * 64 + n * 16 + fr];
    float fsum = 0.0f;
#pragma unroll
    for (int m = 0; m < 4; ++m) {
#pragma unroll
        for (int j = 0; j < 4; ++j) {
            float xn = n2[xbase + wr * 64 + m * 16 + g * 4 + j];
#pragma unroll
            for (int n = 0; n < 4; ++n) {
                float d2 = xn + yn[n] - 2.0f * acc[m][n][j];
                d2 = fmaxf(d2, 0.0f);
                fsum += __expf(-GAMMA * d2);
            }
        }
    }

#pragma unroll
    for (int off = 32; off; off >>= 1) fsum += __shfl_xor(fsum, off);
    if (l == 0) wsum[w] = (double)fsum;
    __syncthreads();
    if (tid == 0) {
        double tot = wsum[0] + wsum[1] + wsum[2] + wsum[3];
        double wgt = ((xbase < NH) == (ybase < NH)) ? 1.0 : -1.0;
        if (r != c) wgt *= 2.0; // off-diagonal tiles counted twice (symmetry)
        partial[blockIdx.x] = wgt * tot;
    }
}

// ---------------- final reduce ----------------
__global__ void reduce_partials_kernel(const double* __restrict__ partial,
                                       float* __restrict__ out) {
    __shared__ double ws[4];
    double s = 0.0;
    for (int i = threadIdx.x; i < NTRI; i += 256) s += partial[i];
#pragma unroll
    for (int off = 32; off; off >>= 1) s += __shfl_xor(s, off);
    if ((threadIdx.x & 63) == 0) ws[threadIdx.x >> 6] = s;
    __syncthreads();
    if (threadIdx.x == 0) {
        double tot = ws[0] + ws[1] + ws[2] + ws[3];
        out[0] = (float)(tot / ((double)NH * (double)NH));
    }
}

extern "C" void kernel_launch(void* const* d_in, const int* in_sizes, int n_in,
                              void* d_out, int out_size, void* d_ws, size_t ws_size,
                              hipStream_t stream) {
    const float* zs = (const float*)d_in[0];
    const float* zt = (const float*)d_in[1];
    float* out = (float*)d_out;

    // workspace layout
    unsigned short* Zh = (unsigned short*)d_ws;                          // 8 MB
    unsigned short* Zl = (unsigned short*)((char*)d_ws + 8388608);       // 8 MB
    float*  n2      = (float*)((char*)d_ws + 16777216);                  // 64 KB
    double* partial = (double*)((char*)d_ws + 16842752);                 // 66 KB

    split_kernel<<<(NTOT * DIM) / (256 * 8), 256, 0, stream>>>(zs, zt, Zh, Zl);
    row_norms_kernel<<<NTOT / 4, 256, 0, stream>>>(zs, zt, n2);
    mmd_mfma_kernel<<<NTRI, 256, 0, stream>>>(Zh, Zl, n2, partial);
    reduce_partials_kernel<<<1, 256, 0, stream>>>(partial, out);
}

// Round 3
// 210.953 us; speedup vs baseline: 5.7901x; 1.2863x over previous
//
#include <hip/hip_runtime.h>

#define NH   8192
#define DIM  256
#define NTOT 16384
#define TILE 256
#define NB   64                   // NTOT / TILE
#define NTRI (NB * (NB + 1) / 2)  // 2080
#define TRIOFF(x) ((x) * (2 * NB + 1 - (x)) / 2)  // x*(129-x)/2

constexpr float GAMMA = 0.00390625f; // 1/256

using short8  = __attribute__((ext_vector_type(8))) short;
using short4v = __attribute__((ext_vector_type(4))) short;
using f32x4   = __attribute__((ext_vector_type(4))) float;

__device__ __forceinline__ unsigned short bf16_rne(float f) {
    unsigned u = __float_as_uint(f);
    u += 0x7FFFu + ((u >> 16) & 1u);
    return (unsigned short)(u >> 16);
}

// ---------------- fused split (fp32 -> bf16 hi/lo) + row norms ----------------
// one wave per row: 64 lanes x 4 floats = 256 = DIM
__global__ void prep_kernel(const float* __restrict__ zs,
                            const float* __restrict__ zt,
                            unsigned short* __restrict__ Zh,
                            unsigned short* __restrict__ Zl,
                            float* __restrict__ n2) {
    int w = threadIdx.x >> 6, l = threadIdx.x & 63;
    int row = blockIdx.x * 4 + w;
    const float* zp = (row < NH) ? zs + (size_t)row * DIM
                                 : zt + (size_t)(row - NH) * DIM;
    float4 v = *(const float4*)(zp + l * 4);
    float s = v.x * v.x + v.y * v.y + v.z * v.z + v.w * v.w;
#pragma unroll
    for (int off = 32; off; off >>= 1) s += __shfl_xor(s, off);
    if (l == 0) n2[row] = s;

    float x[4] = {v.x, v.y, v.z, v.w};
    short4v hv, lv;
#pragma unroll
    for (int j = 0; j < 4; ++j) {
        unsigned short h = bf16_rne(x[j]);
        float hf = __uint_as_float((unsigned)h << 16);
        hv[j] = (short)h;
        lv[j] = (short)bf16_rne(x[j] - hf);
    }
    *(short4v*)(Zh + (size_t)row * DIM + l * 4) = hv;
    *(short4v*)(Zl + (size_t)row * DIM + l * 4) = lv;
}

// ---------------- main: 256x256 tiles, 8 waves, double-buffered LDS ----------------
__global__ __launch_bounds__(512, 2)
void mmd_mfma_kernel(const unsigned short* __restrict__ Zh,
                     const unsigned short* __restrict__ Zl,
                     const float* __restrict__ n2,
                     double* __restrict__ partial) {
    // 2 buffers x {Ah, Al, Bh, Bl} x 256 rows x 32 cols bf16 = 131072 B
    __shared__ __align__(16) unsigned short lds[2][4][8192];

    const int tid = threadIdx.x;
    const int w = tid >> 6, l = tid & 63;
    const int wr = w >> 2, wc = w & 3;   // 2 x 4 wave grid; wave owns 128x64
    const int fr = l & 15;               // fragment row/col within 16
    const int g  = l >> 4;               // k-group 0..3

    // XCD-aware bijective swizzle (2080 % 8 == 0 -> chunked remap is exact)
    int t = ((int)blockIdx.x & 7) * (NTRI / 8) + ((int)blockIdx.x >> 3);

    // linear t -> upper-triangle (r, c), r <= c
    int r = (int)((129.0 - sqrt(129.0 * 129.0 - 8.0 * (double)t)) * 0.5);
    if (r < 0) r = 0;
    if (r > NB - 1) r = NB - 1;
    while (r < NB - 1 && TRIOFF(r + 1) <= t) ++r;
    while (r > 0 && TRIOFF(r) > t) --r;
    const int c = r + (t - TRIOFF(r));
    const int xbase = r * TILE, ybase = c * TILE;

    const unsigned short* gAh = Zh + (size_t)xbase * DIM;
    const unsigned short* gAl = Zl + (size_t)xbase * DIM;
    const unsigned short* gBh = Zh + (size_t)ybase * DIM;
    const unsigned short* gBl = Zl + (size_t)ybase * DIM;

    // swizzled 16B-slot for fragment reads: slot' = g ^ ((fr>>1)&3)
    const int slotp = g ^ ((fr >> 1) & 3);
    const int aoff = (wr * 128 + fr) * 32 + slotp * 8; // shorts; + m*512
    const int boff = (wc * 64  + fr) * 32 + slotp * 8; // shorts; + n*512

    // staging geometry: thread covers 16B at linear offset q*8192 + tid*16 per array
    const int srow0 = tid >> 2;                            // row (q=0); q=1 adds 128
    const int sslot = (tid & 3) ^ ((srow0 >> 1) & 3);      // logical slot (same for q=0/1)
    const int scol  = sslot * 8;                           // element col within chunk
    const unsigned dsto = (unsigned)tid * 8;               // shorts; + q*4096

    f32x4 acc[8][4];
#pragma unroll
    for (int m = 0; m < 8; ++m)
#pragma unroll
        for (int n = 0; n < 4; ++n) acc[m][n] = {0.f, 0.f, 0.f, 0.f};

#define STAGE(KC, P)                                                               \
    {                                                                              \
        _Pragma("unroll")                                                          \
        for (int q = 0; q < 2; ++q) {                                              \
            const int rw = q * 128 + srow0;                                        \
            const size_t go = (size_t)rw * DIM + (KC) + scol;                      \
            unsigned short* d0 = (unsigned short*)&lds[P][0][q * 4096 + dsto];     \
            unsigned short* d1 = (unsigned short*)&lds[P][1][q * 4096 + dsto];     \
            unsigned short* d2 = (unsigned short*)&lds[P][2][q * 4096 + dsto];     \
            unsigned short* d3 = (unsigned short*)&lds[P][3][q * 4096 + dsto];     \
            __builtin_amdgcn_global_load_lds(gAh + go, d0, 16, 0, 0);              \
            __builtin_amdgcn_global_load_lds(gAl + go, d1, 16, 0, 0);              \
            __builtin_amdgcn_global_load_lds(gBh + go, d2, 16, 0, 0);              \
            __builtin_amdgcn_global_load_lds(gBl + go, d3, 16, 0, 0);              \
        }                                                                          \
    }

    STAGE(0, 0);
    __syncthreads();

    for (int ch = 0; ch < 8; ++ch) {
        const int p = ch & 1;
        if (ch < 7) STAGE((ch + 1) * 32, p ^ 1);

        const unsigned short* A_h = lds[p][0];
        const unsigned short* A_l = lds[p][1];
        const unsigned short* B_h = lds[p][2];
        const unsigned short* B_l = lds[p][3];

        short8 bh[4], bl[4];
#pragma unroll
        for (int n = 0; n < 4; ++n) {
            bh[n] = *(const short8*)&B_h[boff + n * 512];
            bl[n] = *(const short8*)&B_l[boff + n * 512];
        }
        __builtin_amdgcn_s_setprio(1);
#pragma unroll
        for (int m = 0; m < 8; ++m) {
            short8 ah = *(const short8*)&A_h[aoff + m * 512];
            short8 al = *(const short8*)&A_l[aoff + m * 512];
#pragma unroll
            for (int n = 0; n < 4; ++n) {
                acc[m][n] = __builtin_amdgcn_mfma_f32_16x16x32_bf16(ah, bh[n], acc[m][n], 0, 0, 0);
                acc[m][n] = __builtin_amdgcn_mfma_f32_16x16x32_bf16(ah, bl[n], acc[m][n], 0, 0, 0);
                acc[m][n] = __builtin_amdgcn_mfma_f32_16x16x32_bf16(al, bh[n], acc[m][n], 0, 0, 0);
            }
        }
        __builtin_amdgcn_s_setprio(0);
        __syncthreads();  // reads of lds[p] done; stage writes to lds[p^1] drained
    }

    // epilogue: d2 = |x|^2 + |y|^2 - 2 x.y, exp, sum
    // C/D layout: col = lane&15 (fr), row = (lane>>4)*4 + reg  (verified R2, absmax 0.0)
    float yn[4];
#pragma unroll
    for (int n = 0; n < 4; ++n) yn[n] = n2[ybase + wc * 64 + n * 16 + fr];
    float fsum = 0.0f;
#pragma unroll
    for (int m = 0; m < 8; ++m) {
#pragma unroll
        for (int j = 0; j < 4; ++j) {
            float xn = n2[xbase + wr * 128 + m * 16 + g * 4 + j];
#pragma unroll
            for (int n = 0; n < 4; ++n) {
                float d2 = xn + yn[n] - 2.0f * acc[m][n][j];
                d2 = fmaxf(d2, 0.0f);
                fsum += __expf(-GAMMA * d2);
            }
        }
    }

#pragma unroll
    for (int off = 32; off; off >>= 1) fsum += __shfl_xor(fsum, off);

    double* wsum = (double*)&lds[0][0][0];  // LDS free after last chunk barrier
    if (l == 0) wsum[w] = (double)fsum;
    __syncthreads();
    if (tid == 0) {
        double tot = 0.0;
#pragma unroll
        for (int i = 0; i < 8; ++i) tot += wsum[i];
        double wgt = ((xbase < NH) == (ybase < NH)) ? 1.0 : -1.0;
        if (r != c) wgt *= 2.0; // off-diagonal tiles counted twice (symmetry)
        partial[blockIdx.x] = wgt * tot;
    }
}

// ---------------- final reduce ----------------
__global__ void reduce_partials_kernel(const double* __restrict__ partial,
                                       float* __restrict__ out) {
    __shared__ double ws[4];
    double s = 0.0;
    for (int i = threadIdx.x; i < NTRI; i += 256) s += partial[i];
#pragma unroll
    for (int off = 32; off; off >>= 1) s += __shfl_xor(s, off);
    if ((threadIdx.x & 63) == 0) ws[threadIdx.x >> 6] = s;
    __syncthreads();
    if (threadIdx.x == 0) {
        double tot = ws[0] + ws[1] + ws[2] + ws[3];
        out[0] = (float)(tot / ((double)NH * (double)NH));
    }
}

extern "C" void kernel_launch(void* const* d_in, const int* in_sizes, int n_in,
                              void* d_out, int out_size, void* d_ws, size_t ws_size,
                              hipStream_t stream) {
    const float* zs = (const float*)d_in[0];
    const float* zt = (const float*)d_in[1];
    float* out = (float*)d_out;

    unsigned short* Zh = (unsigned short*)d_ws;                      // 8 MB
    unsigned short* Zl = (unsigned short*)((char*)d_ws + 8388608);   // 8 MB
    float*  n2      = (float*)((char*)d_ws + 16777216);              // 64 KB
    double* partial = (double*)((char*)d_ws + 16842752);             // 16.6 KB

    prep_kernel<<<NTOT / 4, 256, 0, stream>>>(zs, zt, Zh, Zl, n2);
    mmd_mfma_kernel<<<NTRI, 512, 0, stream>>>(Zh, Zl, n2, partial);
    reduce_partials_kernel<<<1, 256, 0, stream>>>(partial, out);
}